// Round 4
// baseline (227.341 us; speedup 1.0000x reference)
//
#include <hip/hip_runtime.h>
#include <math.h>

// ---------------- problem constants ----------------
#define NB        512
#define ND        32
#define NCOND     30
#define NS        21                  // NB_STEPS+1 quadrature nodes
#define NBD       (NB*ND)             // 16384
#define NROWS     (NBD*NS)            // 344064 MLP evaluations
#define MBLK      128                 // rows per block
#define NBLOCKS   (NROWS/MBLK)        // 2688

// packed-weight element counts (ushort)
#define W0P_ELEMS (1*16*64*8)         // 8192
#define W1P_ELEMS (8*16*64*8)         // 65536
#define W3P_ELEMS (8*64*8)            // 4096  (zero-padded W3 as A-fragments)
#define WP_TOTAL  (W0P_ELEMS + 2*W1P_ELEMS + W3P_ELEMS)  // 143360

typedef __bf16 bf8 __attribute__((ext_vector_type(8)));
typedef float  fx4 __attribute__((ext_vector_type(4)));
typedef unsigned short us8 __attribute__((ext_vector_type(8)));

__device__ __forceinline__ unsigned short f2bf(float f) {
  unsigned int u = __float_as_uint(f);
  u += 0x7FFFu + ((u >> 16) & 1u);        // round-to-nearest-even
  return (unsigned short)(u >> 16);
}

// ---------------- kernel 1: pack weights to bf16 MFMA fragment order ----------
// Fragment layout (serves BOTH as B-frag of W and A-frag of W^T):
//   p = ((kt*16+ct)*64+lane)*8 + i  holds W[kt*32+(lane>>4)*8+i][ct*16+(lane&15)]
// W3 region: A-frag of W3^T zero-padded to 16 rows (only row 0 nonzero).
__global__ void prep_pack(const float* __restrict__ W0,
                          const float* __restrict__ W1,
                          const float* __restrict__ W2,
                          const float* __restrict__ W3,
                          unsigned short* __restrict__ wp) {
  int t = blockIdx.x * blockDim.x + threadIdx.x;   // one thread = one 8-elem frag
  if (t >= WP_TOTAL / 8) return;
  int base = t * 8;
  us8 out;
  if (base >= W0P_ELEMS + 2 * W1P_ELEMS) {         // W3 region
    int rem  = base - (W0P_ELEMS + 2 * W1P_ELEMS);
    int lane = (rem >> 3) & 63;
    int ktl  = rem >> 9;
    int k0   = ktl * 32 + (lane >> 4) * 8;
#pragma unroll
    for (int i = 0; i < 8; ++i)
      out[i] = ((lane & 15) == 0) ? f2bf(W3[k0 + i]) : (unsigned short)0;
  } else {
    const float* W; int rem, K;
    if (base < W0P_ELEMS)                  { W = W0; rem = base;                 K = 31;  }
    else if (base < W0P_ELEMS + W1P_ELEMS) { W = W1; rem = base - W0P_ELEMS;     K = 256; }
    else                                   { W = W2; rem = base - W0P_ELEMS - W1P_ELEMS; K = 256; }
    int lane = (rem >> 3) & 63;
    int ct   = (rem >> 9) & 15;
    int ktl  =  rem >> 13;
    int j  = ct * 16 + (lane & 15);
    int k0 = ktl * 32 + (lane >> 4) * 8;
#pragma unroll
    for (int i = 0; i < 8; ++i) {
      int k = k0 + i;
      out[i] = (k < K) ? f2bf(W[k * 256 + j]) : (unsigned short)0;
    }
  }
  *reinterpret_cast<us8*>(wp + base) = out;
}

// ---------------- fused MLP kernel ----------------
// 8 waves = 2 rgrp (64 rows) x 4 cgrp (64 neurons). Block = 128 rows.
// Wave = 4 row-tiles x 4 col-tiles -> weight-frag reuse x4, act-frag reuse x4.
// Single 64KB activation buffer: read-phase ... barrier ... store-phase ...
// barrier (in-place overwrite is safe once all reads completed).
// Swapped MFMA: D = mfma(W^T, act^T) -> lane holds act-row m = (lane&15)-slot,
// neurons n = ct*16+(lane>>4)*4+reg (4 consecutive -> packed ds_write_b64).
// LDS byte-swizzle ^((m&15)<<4): conflict-free b128 reads / 2-way-free writes.

__device__ __forceinline__ void act_store(unsigned char* dst, int rgrp, int cgrp,
                                          int colb, int khalf,
                                          const fx4 acc[4][4],
                                          const float* __restrict__ bias) {
  float4 bv[4];
#pragma unroll
  for (int ct = 0; ct < 4; ++ct)
    bv[ct] = *reinterpret_cast<const float4*>(bias + (cgrp * 4 + ct) * 16 + khalf * 4);
#pragma unroll
  for (int rt = 0; rt < 4; ++rt) {
    int m = rgrp * 64 + rt * 16 + colb;
    unsigned int base = (unsigned int)(m * 512);
    unsigned int swz  = (unsigned int)((m & 15) << 4);
#pragma unroll
    for (int ct = 0; ct < 4; ++ct) {
      int n0 = (cgrp * 4 + ct) * 16 + khalf * 4;
      float v0 = fmaxf(acc[rt][ct][0] + bv[ct].x, 0.f);
      float v1 = fmaxf(acc[rt][ct][1] + bv[ct].y, 0.f);
      float v2 = fmaxf(acc[rt][ct][2] + bv[ct].z, 0.f);
      float v3 = fmaxf(acc[rt][ct][3] + bv[ct].w, 0.f);
      unsigned int p0, p1;
      asm("v_cvt_pk_bf16_f32 %0, %1, %2" : "=v"(p0) : "v"(v0), "v"(v1));
      asm("v_cvt_pk_bf16_f32 %0, %1, %2" : "=v"(p1) : "v"(v2), "v"(v3));
      uint2 pk; pk.x = p0; pk.y = p1;
      *reinterpret_cast<uint2*>(dst + ((base + (unsigned int)(n0 * 2)) ^ swz)) = pk;
    }
  }
}

// accumulate one 256->256 dense layer (8 K-steps) into acc
__device__ __forceinline__ void dense256(const unsigned char* act,
                                         const unsigned short* __restrict__ wb,
                                         int rgrp, int cgrp, int colb, int khalf,
                                         fx4 acc[4][4]) {
#pragma unroll
  for (int rt = 0; rt < 4; ++rt)
#pragma unroll
    for (int ct = 0; ct < 4; ++ct) acc[rt][ct] = fx4{0.f, 0.f, 0.f, 0.f};
#pragma unroll
  for (int kt = 0; kt < 8; ++kt) {
    bf8 w[4];
#pragma unroll
    for (int ct = 0; ct < 4; ++ct)
      w[ct] = *reinterpret_cast<const bf8*>(wb + ((kt * 16 + cgrp * 4 + ct) * 64 + (khalf * 16 + colb)) * 8);
#pragma unroll
    for (int rt = 0; rt < 4; ++rt) {
      int m = rgrp * 64 + rt * 16 + colb;
      unsigned int off = ((unsigned int)(m * 512 + kt * 64 + khalf * 16))
                       ^ ((unsigned int)((m & 15) << 4));
      bf8 a = *reinterpret_cast<const bf8*>(act + off);
#pragma unroll
      for (int ct = 0; ct < 4; ++ct)
        acc[rt][ct] = __builtin_amdgcn_mfma_f32_16x16x32_bf16(w[ct], a, acc[rt][ct], 0, 0, 0);
    }
  }
}

__global__ __launch_bounds__(512, 4)
void mlp_kernel(const float* __restrict__ x, const float* __restrict__ h,
                const float* __restrict__ b0, const float* __restrict__ b1,
                const float* __restrict__ b2, const float* __restrict__ b3,
                const unsigned short* __restrict__ wp,
                float* __restrict__ fbuf) {
  __shared__ __align__(16) unsigned char ldsAct[128 * 512];  // 64 KiB
  __shared__ __align__(16) unsigned char ldsIn[128 * 64];    // 8 KiB

  int tid  = threadIdx.x;
  int wv   = tid >> 6;
  int lane = tid & 63;
  int rgrp = wv >> 2;            // 0..1 : 64-row half
  int cgrp = wv & 3;             // 0..3 : 64-neuron group
  int colb  = lane & 15;
  int khalf = lane >> 4;
  int R0 = blockIdx.x * MBLK;

  // ---- stage layer-0 input [128 rows][32 bf16] into ldsIn ----
  {
    int r = tid >> 2;                   // 0..127
    int q = tid & 3;                    // 8-col chunk
    int gr = R0 + r;
    unsigned int bd = (unsigned int)gr / NS;
    int s = gr - (int)bd * NS;
    float xv = x[bd];
    float node = xv * (cosf((float)s * 0.15707963267948966f) + 1.0f) * 0.5f;
    const float* hrow = h + bd * NCOND;
    us8 au;
#pragma unroll
    for (int i = 0; i < 8; ++i) {
      int c = q * 8 + i;
      float v;
      if (c == 0)       v = node;
      else if (c <= 30) v = hrow[c - 1];
      else              v = 0.0f;
      au[i] = f2bf(v);
    }
    unsigned int off = (unsigned int)(r * 64 + q * 16) ^ (unsigned int)((r & 3) << 4);
    *reinterpret_cast<us8*>(ldsIn + off) = au;
  }
  __syncthreads();

  fx4 acc[4][4];

  // ======== layer 0: K=32 (one K-step), read ldsIn, store ldsAct ========
  {
#pragma unroll
    for (int rt = 0; rt < 4; ++rt)
#pragma unroll
      for (int ct = 0; ct < 4; ++ct) acc[rt][ct] = fx4{0.f, 0.f, 0.f, 0.f};
    bf8 w[4];
#pragma unroll
    for (int ct = 0; ct < 4; ++ct)
      w[ct] = *reinterpret_cast<const bf8*>(wp + ((cgrp * 4 + ct) * 64 + lane) * 8);
#pragma unroll
    for (int rt = 0; rt < 4; ++rt) {
      int m = rgrp * 64 + rt * 16 + colb;
      unsigned int off = (unsigned int)(m * 64 + khalf * 16) ^ (unsigned int)((m & 3) << 4);
      bf8 a = *reinterpret_cast<const bf8*>(ldsIn + off);
#pragma unroll
      for (int ct = 0; ct < 4; ++ct)
        acc[rt][ct] = __builtin_amdgcn_mfma_f32_16x16x32_bf16(w[ct], a, acc[rt][ct], 0, 0, 0);
    }
    act_store(ldsAct, rgrp, cgrp, colb, khalf, acc, b0);   // first write: no barrier needed
  }
  __syncthreads();

  const unsigned short* wb1 = wp + W0P_ELEMS;
  const unsigned short* wb2 = wp + W0P_ELEMS + W1P_ELEMS;
  const unsigned short* w3p = wp + W0P_ELEMS + 2 * W1P_ELEMS;

  // ======== layer 1 (in-place: read, barrier, store, barrier) ========
  dense256(ldsAct, wb1, rgrp, cgrp, colb, khalf, acc);
  __syncthreads();
  act_store(ldsAct, rgrp, cgrp, colb, khalf, acc, b1);
  __syncthreads();

  // ======== layer 2 ========
  dense256(ldsAct, wb2, rgrp, cgrp, colb, khalf, acc);
  __syncthreads();
  act_store(ldsAct, rgrp, cgrp, colb, khalf, acc, b2);
  __syncthreads();

  // ======== layer 3: 256 -> 1 via MFMA with zero-padded W3^T (cgrp 0 only) ====
  if (cgrp == 0) {
    fx4 a3[4];
#pragma unroll
    for (int rt = 0; rt < 4; ++rt) a3[rt] = fx4{0.f, 0.f, 0.f, 0.f};
#pragma unroll
    for (int kt = 0; kt < 8; ++kt) {
      bf8 w3f = *reinterpret_cast<const bf8*>(w3p + (kt * 64 + lane) * 8);
#pragma unroll
      for (int rt = 0; rt < 4; ++rt) {
        int m = rgrp * 64 + rt * 16 + colb;
        unsigned int off = ((unsigned int)(m * 512 + kt * 64 + khalf * 16))
                         ^ ((unsigned int)((m & 15) << 4));
        bf8 a = *reinterpret_cast<const bf8*>(ldsAct + off);
        a3[rt] = __builtin_amdgcn_mfma_f32_16x16x32_bf16(w3f, a, a3[rt], 0, 0, 0);
      }
    }
    if (lane < 16) {
      float bias3 = b3[0];
#pragma unroll
      for (int rt = 0; rt < 4; ++rt) {
        float y = a3[rt][0] + bias3;
        float f = (y > 0.f) ? (y + 1.f) : expf(y);   // elu(y)+1
        fbuf[R0 + rgrp * 64 + rt * 16 + lane] = f;
      }
    }
  }
}

// ---------------- kernel 3: Clenshaw-Curtis reduction -> z, jac ----------------
__global__ void reduce_kernel(const float* __restrict__ x, const float* __restrict__ h,
                              const float* __restrict__ fbuf, float* __restrict__ out) {
  __shared__ float ccw[NS];
  int tid = threadIdx.x;
  if (tid < NS) {
    double acc = 0.0;
#pragma unroll
    for (int i = 0; i <= 20; i += 2) {
      double wi = (i == 0) ? 1.0 : 2.0 / (1.0 - (double)(i * i));
      acc += cos((double)(i * tid) * 3.141592653589793 / 20.0) * wi;
    }
    double edge = (tid == 0 || tid == 20) ? 0.5 : 1.0;
    ccw[tid] = (float)(acc * 0.1 * edge);          // * 2/nb_steps * edge
  }
  __syncthreads();
  int t = blockIdx.x * blockDim.x + tid;
  if (t >= NBD) return;
  const float* fb = fbuf + t * NS;
  float acc = 0.f;
#pragma unroll
  for (int i = 0; i < NS; ++i) acc += fb[i] * ccw[i];
  float z = acc * x[t] * 0.5f + h[t * NCOND];
  out[t] = z;                     // z_est + h[:,:,0]
  out[NBD + t] = fb[0];           // jac = f at node s=0 (steps[0]==1 -> input == [x,h])
}

// ---------------- launcher ----------------
extern "C" void kernel_launch(void* const* d_in, const int* in_sizes, int n_in,
                              void* d_out, int out_size, void* d_ws, size_t ws_size,
                              hipStream_t stream) {
  (void)in_sizes; (void)n_in; (void)out_size; (void)ws_size;
  const float* x  = (const float*)d_in[0];
  const float* h  = (const float*)d_in[1];
  const float* W0 = (const float*)d_in[2];
  const float* b0 = (const float*)d_in[3];
  const float* W1 = (const float*)d_in[4];
  const float* b1 = (const float*)d_in[5];
  const float* W2 = (const float*)d_in[6];
  const float* b2 = (const float*)d_in[7];
  const float* W3 = (const float*)d_in[8];
  const float* b3 = (const float*)d_in[9];

  unsigned short* wp = (unsigned short*)d_ws;
  float* fbuf = (float*)((char*)d_ws + WP_TOTAL * sizeof(unsigned short));
  float* out  = (float*)d_out;

  prep_pack<<<(WP_TOTAL / 8 + 255) / 256, 256, 0, stream>>>(W0, W1, W2, W3, wp);
  mlp_kernel<<<NBLOCKS, 512, 0, stream>>>(x, h, b0, b1, b2, b3, wp, fbuf);
  reduce_kernel<<<(NBD + 255) / 256, 256, 0, stream>>>(x, h, fbuf, out);
}

// Round 5
// 196.536 us; speedup vs baseline: 1.1567x; 1.1567x over previous
//
#include <hip/hip_runtime.h>
#include <math.h>

// ---------------- problem constants ----------------
#define NB        512
#define ND        32
#define NCOND     30
#define NS        21                  // NB_STEPS+1 quadrature nodes
#define NBD       (NB*ND)             // 16384
#define NROWS     (NBD*NS)            // 344064 MLP evaluations
#define MBLK      128                 // rows per block
#define NBLOCKS   (NROWS/MBLK)        // 2688

// packed-weight element counts (ushort)
#define W0P_ELEMS (1*16*64*8)         // 8192
#define W1P_ELEMS (8*16*64*8)         // 65536
#define W3P_ELEMS (8*64*8)            // 4096  (zero-padded W3 as A-fragments)
#define WP_TOTAL  (W0P_ELEMS + 2*W1P_ELEMS + W3P_ELEMS)  // 143360

typedef __bf16 bf8 __attribute__((ext_vector_type(8)));
typedef float  fx4 __attribute__((ext_vector_type(4)));
typedef unsigned short us8 __attribute__((ext_vector_type(8)));

__device__ __forceinline__ unsigned short f2bf(float f) {
  unsigned int u = __float_as_uint(f);
  u += 0x7FFFu + ((u >> 16) & 1u);        // round-to-nearest-even
  return (unsigned short)(u >> 16);
}

// ---------------- kernel 1: pack weights to bf16 MFMA fragment order ----------
// Fragment layout (serves BOTH as B-frag of W and A-frag of W^T):
//   p = ((kt*16+ct)*64+lane)*8 + i  holds W[kt*32+(lane>>4)*8+i][ct*16+(lane&15)]
// W3 region: A-frag of W3^T zero-padded to 16 rows (only row 0 nonzero).
__global__ void prep_pack(const float* __restrict__ W0,
                          const float* __restrict__ W1,
                          const float* __restrict__ W2,
                          const float* __restrict__ W3,
                          unsigned short* __restrict__ wp) {
  int t = blockIdx.x * blockDim.x + threadIdx.x;   // one thread = one 8-elem frag
  if (t >= WP_TOTAL / 8) return;
  int base = t * 8;
  us8 out;
  if (base >= W0P_ELEMS + 2 * W1P_ELEMS) {         // W3 region
    int rem  = base - (W0P_ELEMS + 2 * W1P_ELEMS);
    int lane = (rem >> 3) & 63;
    int ktl  = rem >> 9;
    int k0   = ktl * 32 + (lane >> 4) * 8;
#pragma unroll
    for (int i = 0; i < 8; ++i)
      out[i] = ((lane & 15) == 0) ? f2bf(W3[k0 + i]) : (unsigned short)0;
  } else {
    const float* W; int rem, K;
    if (base < W0P_ELEMS)                  { W = W0; rem = base;                 K = 31;  }
    else if (base < W0P_ELEMS + W1P_ELEMS) { W = W1; rem = base - W0P_ELEMS;     K = 256; }
    else                                   { W = W2; rem = base - W0P_ELEMS - W1P_ELEMS; K = 256; }
    int lane = (rem >> 3) & 63;
    int ct   = (rem >> 9) & 15;
    int ktl  =  rem >> 13;
    int j  = ct * 16 + (lane & 15);
    int k0 = ktl * 32 + (lane >> 4) * 8;
#pragma unroll
    for (int i = 0; i < 8; ++i) {
      int k = k0 + i;
      out[i] = (k < K) ? f2bf(W[k * 256 + j]) : (unsigned short)0;
    }
  }
  *reinterpret_cast<us8*>(wp + base) = out;
}

// ---------------- fused MLP kernel ----------------
// 8 waves = 2 rgrp (64 rows) x 4 cgrp (64 neurons). Block = 128 rows.
// Wave = 4 row-tiles x 4 col-tiles -> weight-frag reuse x4, act-frag reuse x4.
// EVERYTHING inlined in the kernel body with local acc (NO array function
// params: round-4 showed char*-aliasing blocks SROA -> 320 B/thread scratch).
// Single 64KB activation buffer, in-place: read ... barrier ... store ... barrier.
// Swapped MFMA: D = mfma(W^T, act^T) -> lane holds act-row m, 4 consecutive
// neurons per reg quad -> packed ds_write_b64. Swizzle ^((m&15)<<4).

// dense-layer read+MFMA phase (acc, w are enclosing locals; static indices only)
#define DENSE256(WBASE)                                                          \
  {                                                                              \
    _Pragma("unroll")                                                            \
    for (int rt = 0; rt < 4; ++rt)                                               \
      _Pragma("unroll")                                                          \
      for (int ct = 0; ct < 4; ++ct) acc[rt][ct] = fx4{0.f, 0.f, 0.f, 0.f};      \
    _Pragma("unroll")                                                            \
    for (int kt = 0; kt < 8; ++kt) {                                             \
      bf8 w0 = *reinterpret_cast<const bf8*>((WBASE) + ((kt * 16 + cgrp * 4 + 0) * 64 + lane) * 8); \
      bf8 w1 = *reinterpret_cast<const bf8*>((WBASE) + ((kt * 16 + cgrp * 4 + 1) * 64 + lane) * 8); \
      bf8 w2 = *reinterpret_cast<const bf8*>((WBASE) + ((kt * 16 + cgrp * 4 + 2) * 64 + lane) * 8); \
      bf8 w3 = *reinterpret_cast<const bf8*>((WBASE) + ((kt * 16 + cgrp * 4 + 3) * 64 + lane) * 8); \
      _Pragma("unroll")                                                          \
      for (int rt = 0; rt < 4; ++rt) {                                           \
        int m = rgrp * 64 + rt * 16 + colb;                                      \
        unsigned int off = ((unsigned int)(m * 512 + kt * 64 + khalf * 16))      \
                         ^ ((unsigned int)((m & 15) << 4));                      \
        bf8 a = *reinterpret_cast<const bf8*>(ldsAct + off);                     \
        acc[rt][0] = __builtin_amdgcn_mfma_f32_16x16x32_bf16(w0, a, acc[rt][0], 0, 0, 0); \
        acc[rt][1] = __builtin_amdgcn_mfma_f32_16x16x32_bf16(w1, a, acc[rt][1], 0, 0, 0); \
        acc[rt][2] = __builtin_amdgcn_mfma_f32_16x16x32_bf16(w2, a, acc[rt][2], 0, 0, 0); \
        acc[rt][3] = __builtin_amdgcn_mfma_f32_16x16x32_bf16(w3, a, acc[rt][3], 0, 0, 0); \
      }                                                                          \
    }                                                                            \
  }

// bias + ReLU + bf16-pack + ds_write_b64 store of acc into ldsAct
#define ACT_STORE(BIAS)                                                          \
  {                                                                              \
    float4 bv0 = *reinterpret_cast<const float4*>((BIAS) + (cgrp * 4 + 0) * 16 + khalf * 4); \
    float4 bv1 = *reinterpret_cast<const float4*>((BIAS) + (cgrp * 4 + 1) * 16 + khalf * 4); \
    float4 bv2 = *reinterpret_cast<const float4*>((BIAS) + (cgrp * 4 + 2) * 16 + khalf * 4); \
    float4 bv3 = *reinterpret_cast<const float4*>((BIAS) + (cgrp * 4 + 3) * 16 + khalf * 4); \
    _Pragma("unroll")                                                            \
    for (int rt = 0; rt < 4; ++rt) {                                             \
      int m = rgrp * 64 + rt * 16 + colb;                                        \
      unsigned int sbase = (unsigned int)(m * 512);                              \
      unsigned int swz   = (unsigned int)((m & 15) << 4);                        \
      _Pragma("unroll")                                                          \
      for (int ct = 0; ct < 4; ++ct) {                                           \
        float4 bv = (ct == 0) ? bv0 : (ct == 1) ? bv1 : (ct == 2) ? bv2 : bv3;   \
        int n0 = (cgrp * 4 + ct) * 16 + khalf * 4;                               \
        float v0 = fmaxf(acc[rt][ct][0] + bv.x, 0.f);                            \
        float v1 = fmaxf(acc[rt][ct][1] + bv.y, 0.f);                            \
        float v2 = fmaxf(acc[rt][ct][2] + bv.z, 0.f);                            \
        float v3 = fmaxf(acc[rt][ct][3] + bv.w, 0.f);                            \
        unsigned int p0, p1;                                                     \
        asm("v_cvt_pk_bf16_f32 %0, %1, %2" : "=v"(p0) : "v"(v0), "v"(v1));       \
        asm("v_cvt_pk_bf16_f32 %0, %1, %2" : "=v"(p1) : "v"(v2), "v"(v3));       \
        uint2 pk; pk.x = p0; pk.y = p1;                                          \
        *reinterpret_cast<uint2*>(ldsAct + ((sbase + (unsigned int)(n0 * 2)) ^ swz)) = pk; \
      }                                                                          \
    }                                                                            \
  }

__global__ __launch_bounds__(512, 4)
void mlp_kernel(const float* __restrict__ x, const float* __restrict__ h,
                const float* __restrict__ b0, const float* __restrict__ b1,
                const float* __restrict__ b2, const float* __restrict__ b3,
                const unsigned short* __restrict__ wp,
                float* __restrict__ fbuf) {
  __shared__ __align__(16) unsigned char ldsAct[128 * 512];  // 64 KiB
  __shared__ __align__(16) unsigned char ldsIn[128 * 64];    // 8 KiB

  int tid  = threadIdx.x;
  int wv   = tid >> 6;
  int lane = tid & 63;
  int rgrp = wv >> 2;            // 0..1 : 64-row half
  int cgrp = wv & 3;             // 0..3 : 64-neuron group
  int colb  = lane & 15;
  int khalf = lane >> 4;
  int R0 = blockIdx.x * MBLK;

  // ---- stage layer-0 input [128 rows][32 bf16] into ldsIn ----
  {
    int r = tid >> 2;                   // 0..127
    int q = tid & 3;                    // 8-col chunk
    int gr = R0 + r;
    unsigned int bd = (unsigned int)gr / NS;
    int s = gr - (int)bd * NS;
    float xv = x[bd];
    float node = xv * (cosf((float)s * 0.15707963267948966f) + 1.0f) * 0.5f;
    const float* hrow = h + bd * NCOND;
    us8 au;
#pragma unroll
    for (int i = 0; i < 8; ++i) {
      int c = q * 8 + i;
      float v;
      if (c == 0)       v = node;
      else if (c <= 30) v = hrow[c - 1];
      else              v = 0.0f;
      au[i] = f2bf(v);
    }
    unsigned int off = (unsigned int)(r * 64 + q * 16) ^ (unsigned int)((r & 3) << 4);
    *reinterpret_cast<us8*>(ldsIn + off) = au;
  }
  __syncthreads();

  fx4 acc[4][4];

  // ======== layer 0: K=32 (one K-step), read ldsIn, store ldsAct ========
  {
#pragma unroll
    for (int rt = 0; rt < 4; ++rt)
#pragma unroll
      for (int ct = 0; ct < 4; ++ct) acc[rt][ct] = fx4{0.f, 0.f, 0.f, 0.f};
    bf8 w0 = *reinterpret_cast<const bf8*>(wp + ((cgrp * 4 + 0) * 64 + lane) * 8);
    bf8 w1 = *reinterpret_cast<const bf8*>(wp + ((cgrp * 4 + 1) * 64 + lane) * 8);
    bf8 w2 = *reinterpret_cast<const bf8*>(wp + ((cgrp * 4 + 2) * 64 + lane) * 8);
    bf8 w3 = *reinterpret_cast<const bf8*>(wp + ((cgrp * 4 + 3) * 64 + lane) * 8);
#pragma unroll
    for (int rt = 0; rt < 4; ++rt) {
      int m = rgrp * 64 + rt * 16 + colb;
      unsigned int off = (unsigned int)(m * 64 + khalf * 16) ^ (unsigned int)((m & 3) << 4);
      bf8 a = *reinterpret_cast<const bf8*>(ldsIn + off);
      acc[rt][0] = __builtin_amdgcn_mfma_f32_16x16x32_bf16(w0, a, acc[rt][0], 0, 0, 0);
      acc[rt][1] = __builtin_amdgcn_mfma_f32_16x16x32_bf16(w1, a, acc[rt][1], 0, 0, 0);
      acc[rt][2] = __builtin_amdgcn_mfma_f32_16x16x32_bf16(w2, a, acc[rt][2], 0, 0, 0);
      acc[rt][3] = __builtin_amdgcn_mfma_f32_16x16x32_bf16(w3, a, acc[rt][3], 0, 0, 0);
    }
    ACT_STORE(b0);                       // first write to ldsAct: no barrier needed
  }
  __syncthreads();

  const unsigned short* wb1 = wp + W0P_ELEMS;
  const unsigned short* wb2 = wp + W0P_ELEMS + W1P_ELEMS;
  const unsigned short* w3p = wp + W0P_ELEMS + 2 * W1P_ELEMS;

  // ======== layer 1 (in-place: read, barrier, store, barrier) ========
  DENSE256(wb1);
  __syncthreads();
  ACT_STORE(b1);
  __syncthreads();

  // ======== layer 2 ========
  DENSE256(wb2);
  __syncthreads();
  ACT_STORE(b2);
  __syncthreads();

  // ======== layer 3: 256 -> 1 via MFMA with zero-padded W3^T (cgrp 0 only) ====
  if (cgrp == 0) {
    fx4 a30 = fx4{0.f, 0.f, 0.f, 0.f};
    fx4 a31 = fx4{0.f, 0.f, 0.f, 0.f};
    fx4 a32 = fx4{0.f, 0.f, 0.f, 0.f};
    fx4 a33 = fx4{0.f, 0.f, 0.f, 0.f};
#pragma unroll
    for (int kt = 0; kt < 8; ++kt) {
      bf8 w3f = *reinterpret_cast<const bf8*>(w3p + (kt * 64 + lane) * 8);
#pragma unroll
      for (int rt = 0; rt < 4; ++rt) {
        int m = rgrp * 64 + rt * 16 + colb;
        unsigned int off = ((unsigned int)(m * 512 + kt * 64 + khalf * 16))
                         ^ ((unsigned int)((m & 15) << 4));
        bf8 a = *reinterpret_cast<const bf8*>(ldsAct + off);
        if      (rt == 0) a30 = __builtin_amdgcn_mfma_f32_16x16x32_bf16(w3f, a, a30, 0, 0, 0);
        else if (rt == 1) a31 = __builtin_amdgcn_mfma_f32_16x16x32_bf16(w3f, a, a31, 0, 0, 0);
        else if (rt == 2) a32 = __builtin_amdgcn_mfma_f32_16x16x32_bf16(w3f, a, a32, 0, 0, 0);
        else              a33 = __builtin_amdgcn_mfma_f32_16x16x32_bf16(w3f, a, a33, 0, 0, 0);
      }
    }
    if (lane < 16) {
      float bias3 = b3[0];
#pragma unroll
      for (int rt = 0; rt < 4; ++rt) {
        float y = ((rt == 0) ? a30[0] : (rt == 1) ? a31[0] : (rt == 2) ? a32[0] : a33[0]) + bias3;
        float f = (y > 0.f) ? (y + 1.f) : expf(y);   // elu(y)+1
        fbuf[R0 + rgrp * 64 + rt * 16 + lane] = f;
      }
    }
  }
}

// ---------------- kernel 3: Clenshaw-Curtis reduction -> z, jac ----------------
__global__ void reduce_kernel(const float* __restrict__ x, const float* __restrict__ h,
                              const float* __restrict__ fbuf, float* __restrict__ out) {
  __shared__ float ccw[NS];
  int tid = threadIdx.x;
  if (tid < NS) {
    double acc = 0.0;
#pragma unroll
    for (int i = 0; i <= 20; i += 2) {
      double wi = (i == 0) ? 1.0 : 2.0 / (1.0 - (double)(i * i));
      acc += cos((double)(i * tid) * 3.141592653589793 / 20.0) * wi;
    }
    double edge = (tid == 0 || tid == 20) ? 0.5 : 1.0;
    ccw[tid] = (float)(acc * 0.1 * edge);          // * 2/nb_steps * edge
  }
  __syncthreads();
  int t = blockIdx.x * blockDim.x + tid;
  if (t >= NBD) return;
  const float* fb = fbuf + t * NS;
  float acc = 0.f;
#pragma unroll
  for (int i = 0; i < NS; ++i) acc += fb[i] * ccw[i];
  float z = acc * x[t] * 0.5f + h[t * NCOND];
  out[t] = z;                     // z_est + h[:,:,0]
  out[NBD + t] = fb[0];           // jac = f at node s=0 (steps[0]==1 -> input == [x,h])
}

// ---------------- launcher ----------------
extern "C" void kernel_launch(void* const* d_in, const int* in_sizes, int n_in,
                              void* d_out, int out_size, void* d_ws, size_t ws_size,
                              hipStream_t stream) {
  (void)in_sizes; (void)n_in; (void)out_size; (void)ws_size;
  const float* x  = (const float*)d_in[0];
  const float* h  = (const float*)d_in[1];
  const float* W0 = (const float*)d_in[2];
  const float* b0 = (const float*)d_in[3];
  const float* W1 = (const float*)d_in[4];
  const float* b1 = (const float*)d_in[5];
  const float* W2 = (const float*)d_in[6];
  const float* b2 = (const float*)d_in[7];
  const float* W3 = (const float*)d_in[8];
  const float* b3 = (const float*)d_in[9];

  unsigned short* wp = (unsigned short*)d_ws;
  float* fbuf = (float*)((char*)d_ws + WP_TOTAL * sizeof(unsigned short));
  float* out  = (float*)d_out;

  prep_pack<<<(WP_TOTAL / 8 + 255) / 256, 256, 0, stream>>>(W0, W1, W2, W3, wp);
  mlp_kernel<<<NBLOCKS, 512, 0, stream>>>(x, h, b0, b1, b2, b3, wp, fbuf);
  reduce_kernel<<<(NBD + 255) / 256, 256, 0, stream>>>(x, h, fbuf, out);
}

// Round 6
// 123.722 us; speedup vs baseline: 1.8375x; 1.5885x over previous
//
#include <hip/hip_runtime.h>
#include <math.h>

// ---------------- problem constants ----------------
#define NB        512
#define ND        32
#define NCOND     30
#define NS        21                  // NB_STEPS+1 quadrature nodes
#define NBD       (NB*ND)             // 16384
#define NROWS     (NBD*NS)            // 344064 MLP evaluations
#define MBLK      128                 // rows per block
#define NBLOCKS   (NROWS/MBLK)        // 2688

// packed-weight element counts (ushort)
#define W0P_ELEMS (1*16*64*8)         // 8192
#define W1P_ELEMS (8*16*64*8)         // 65536
#define W3P_ELEMS (8*64*8)            // 4096  (zero-padded W3 as A-fragments)
#define WP_TOTAL  (W0P_ELEMS + 2*W1P_ELEMS + W3P_ELEMS)  // 143360

typedef __bf16 bf8 __attribute__((ext_vector_type(8)));
typedef float  fx4 __attribute__((ext_vector_type(4)));
typedef unsigned short us8 __attribute__((ext_vector_type(8)));

__device__ __forceinline__ unsigned short f2bf(float f) {
  unsigned int u = __float_as_uint(f);
  u += 0x7FFFu + ((u >> 16) & 1u);        // round-to-nearest-even
  return (unsigned short)(u >> 16);
}

// ---------------- kernel 1: pack weights to bf16 MFMA fragment order ----------
// Fragment layout (serves BOTH as B-frag of W and A-frag of W^T):
//   p = ((kt*16+ct)*64+lane)*8 + i  holds W[kt*32+(lane>>4)*8+i][ct*16+(lane&15)]
// W3 region: A-frag of W3^T zero-padded to 16 rows (only row 0 nonzero).
__global__ void prep_pack(const float* __restrict__ W0,
                          const float* __restrict__ W1,
                          const float* __restrict__ W2,
                          const float* __restrict__ W3,
                          unsigned short* __restrict__ wp) {
  int t = blockIdx.x * blockDim.x + threadIdx.x;   // one thread = one 8-elem frag
  if (t >= WP_TOTAL / 8) return;
  int base = t * 8;
  us8 out;
  if (base >= W0P_ELEMS + 2 * W1P_ELEMS) {         // W3 region
    int rem  = base - (W0P_ELEMS + 2 * W1P_ELEMS);
    int lane = (rem >> 3) & 63;
    int ktl  = rem >> 9;
    int k0   = ktl * 32 + (lane >> 4) * 8;
#pragma unroll
    for (int i = 0; i < 8; ++i)
      out[i] = ((lane & 15) == 0) ? f2bf(W3[k0 + i]) : (unsigned short)0;
  } else {
    const float* W; int rem, K;
    if (base < W0P_ELEMS)                  { W = W0; rem = base;                 K = 31;  }
    else if (base < W0P_ELEMS + W1P_ELEMS) { W = W1; rem = base - W0P_ELEMS;     K = 256; }
    else                                   { W = W2; rem = base - W0P_ELEMS - W1P_ELEMS; K = 256; }
    int lane = (rem >> 3) & 63;
    int ct   = (rem >> 9) & 15;
    int ktl  =  rem >> 13;
    int j  = ct * 16 + (lane & 15);
    int k0 = ktl * 32 + (lane >> 4) * 8;
#pragma unroll
    for (int i = 0; i < 8; ++i) {
      int k = k0 + i;
      out[i] = (k < K) ? f2bf(W[k * 256 + j]) : (unsigned short)0;
    }
  }
  *reinterpret_cast<us8*>(wp + base) = out;
}

// ---------------- fused MLP kernel ----------------
// 8 waves = 2 rgrp (64 rows) x 4 cgrp (64 neurons). Block = 128 rows.
// Wave = 4 row-tiles x 4 col-tiles -> weight-frag reuse x4, act-frag reuse x4.
// launch_bounds(512,2): round-5 showed (512,4) caps the allocator at 64 VGPR
// (CUDA blocks/CU semantics -> 8 waves/EU) and spills acc[4][4] to scratch
// (307 MB HBM writes). (512,2) -> cap >=128, spill-free, HW still 2 blocks/CU.
// Single 64KB activation buffer, in-place: read ... barrier ... store ... barrier.
// Swapped MFMA: D = mfma(W^T, act^T) -> lane holds act-row m, 4 consecutive
// neurons per reg quad -> packed ds_write_b64. Swizzle ^((m&15)<<4).

// dense-layer read+MFMA phase (acc is an enclosing local; static indices only)
#define DENSE256(WBASE)                                                          \
  {                                                                              \
    _Pragma("unroll")                                                            \
    for (int rt = 0; rt < 4; ++rt)                                               \
      _Pragma("unroll")                                                          \
      for (int ct = 0; ct < 4; ++ct) acc[rt][ct] = fx4{0.f, 0.f, 0.f, 0.f};      \
    _Pragma("unroll")                                                            \
    for (int kt = 0; kt < 8; ++kt) {                                             \
      bf8 w0 = *reinterpret_cast<const bf8*>((WBASE) + ((kt * 16 + cgrp * 4 + 0) * 64 + lane) * 8); \
      bf8 w1 = *reinterpret_cast<const bf8*>((WBASE) + ((kt * 16 + cgrp * 4 + 1) * 64 + lane) * 8); \
      bf8 w2 = *reinterpret_cast<const bf8*>((WBASE) + ((kt * 16 + cgrp * 4 + 2) * 64 + lane) * 8); \
      bf8 w3 = *reinterpret_cast<const bf8*>((WBASE) + ((kt * 16 + cgrp * 4 + 3) * 64 + lane) * 8); \
      _Pragma("unroll")                                                          \
      for (int rt = 0; rt < 4; ++rt) {                                           \
        int m = rgrp * 64 + rt * 16 + colb;                                      \
        unsigned int off = ((unsigned int)(m * 512 + kt * 64 + khalf * 16))      \
                         ^ ((unsigned int)((m & 15) << 4));                      \
        bf8 a = *reinterpret_cast<const bf8*>(ldsAct + off);                     \
        acc[rt][0] = __builtin_amdgcn_mfma_f32_16x16x32_bf16(w0, a, acc[rt][0], 0, 0, 0); \
        acc[rt][1] = __builtin_amdgcn_mfma_f32_16x16x32_bf16(w1, a, acc[rt][1], 0, 0, 0); \
        acc[rt][2] = __builtin_amdgcn_mfma_f32_16x16x32_bf16(w2, a, acc[rt][2], 0, 0, 0); \
        acc[rt][3] = __builtin_amdgcn_mfma_f32_16x16x32_bf16(w3, a, acc[rt][3], 0, 0, 0); \
      }                                                                          \
    }                                                                            \
  }

// bias + ReLU + bf16-pack + ds_write_b64 store of acc into ldsAct
#define ACT_STORE(BIAS)                                                          \
  {                                                                              \
    float4 bv0 = *reinterpret_cast<const float4*>((BIAS) + (cgrp * 4 + 0) * 16 + khalf * 4); \
    float4 bv1 = *reinterpret_cast<const float4*>((BIAS) + (cgrp * 4 + 1) * 16 + khalf * 4); \
    float4 bv2 = *reinterpret_cast<const float4*>((BIAS) + (cgrp * 4 + 2) * 16 + khalf * 4); \
    float4 bv3 = *reinterpret_cast<const float4*>((BIAS) + (cgrp * 4 + 3) * 16 + khalf * 4); \
    _Pragma("unroll")                                                            \
    for (int rt = 0; rt < 4; ++rt) {                                             \
      int m = rgrp * 64 + rt * 16 + colb;                                        \
      unsigned int sbase = (unsigned int)(m * 512);                              \
      unsigned int swz   = (unsigned int)((m & 15) << 4);                        \
      _Pragma("unroll")                                                          \
      for (int ct = 0; ct < 4; ++ct) {                                           \
        float4 bv = (ct == 0) ? bv0 : (ct == 1) ? bv1 : (ct == 2) ? bv2 : bv3;   \
        int n0 = (cgrp * 4 + ct) * 16 + khalf * 4;                               \
        float v0 = fmaxf(acc[rt][ct][0] + bv.x, 0.f);                            \
        float v1 = fmaxf(acc[rt][ct][1] + bv.y, 0.f);                            \
        float v2 = fmaxf(acc[rt][ct][2] + bv.z, 0.f);                            \
        float v3 = fmaxf(acc[rt][ct][3] + bv.w, 0.f);                            \
        unsigned int p0, p1;                                                     \
        asm("v_cvt_pk_bf16_f32 %0, %1, %2" : "=v"(p0) : "v"(v0), "v"(v1));       \
        asm("v_cvt_pk_bf16_f32 %0, %1, %2" : "=v"(p1) : "v"(v2), "v"(v3));       \
        uint2 pk; pk.x = p0; pk.y = p1;                                          \
        *reinterpret_cast<uint2*>(ldsAct + ((sbase + (unsigned int)(n0 * 2)) ^ swz)) = pk; \
      }                                                                          \
    }                                                                            \
  }

__global__ __launch_bounds__(512, 2)
void mlp_kernel(const float* __restrict__ x, const float* __restrict__ h,
                const float* __restrict__ b0, const float* __restrict__ b1,
                const float* __restrict__ b2, const float* __restrict__ b3,
                const unsigned short* __restrict__ wp,
                float* __restrict__ fbuf) {
  __shared__ __align__(16) unsigned char ldsAct[128 * 512];  // 64 KiB
  __shared__ __align__(16) unsigned char ldsIn[128 * 64];    // 8 KiB

  int tid  = threadIdx.x;
  int wv   = tid >> 6;
  int lane = tid & 63;
  int rgrp = wv >> 2;            // 0..1 : 64-row half
  int cgrp = wv & 3;             // 0..3 : 64-neuron group
  int colb  = lane & 15;
  int khalf = lane >> 4;
  int R0 = blockIdx.x * MBLK;

  // ---- stage layer-0 input [128 rows][32 bf16] into ldsIn ----
  {
    int r = tid >> 2;                   // 0..127
    int q = tid & 3;                    // 8-col chunk
    int gr = R0 + r;
    unsigned int bd = (unsigned int)gr / NS;
    int s = gr - (int)bd * NS;
    float xv = x[bd];
    float node = xv * (cosf((float)s * 0.15707963267948966f) + 1.0f) * 0.5f;
    const float* hrow = h + bd * NCOND;
    us8 au;
#pragma unroll
    for (int i = 0; i < 8; ++i) {
      int c = q * 8 + i;
      float v;
      if (c == 0)       v = node;
      else if (c <= 30) v = hrow[c - 1];
      else              v = 0.0f;
      au[i] = f2bf(v);
    }
    unsigned int off = (unsigned int)(r * 64 + q * 16) ^ (unsigned int)((r & 3) << 4);
    *reinterpret_cast<us8*>(ldsIn + off) = au;
  }
  __syncthreads();

  fx4 acc[4][4];

  // ======== layer 0: K=32 (one K-step), read ldsIn, store ldsAct ========
  {
#pragma unroll
    for (int rt = 0; rt < 4; ++rt)
#pragma unroll
      for (int ct = 0; ct < 4; ++ct) acc[rt][ct] = fx4{0.f, 0.f, 0.f, 0.f};
    bf8 w0 = *reinterpret_cast<const bf8*>(wp + ((cgrp * 4 + 0) * 64 + lane) * 8);
    bf8 w1 = *reinterpret_cast<const bf8*>(wp + ((cgrp * 4 + 1) * 64 + lane) * 8);
    bf8 w2 = *reinterpret_cast<const bf8*>(wp + ((cgrp * 4 + 2) * 64 + lane) * 8);
    bf8 w3 = *reinterpret_cast<const bf8*>(wp + ((cgrp * 4 + 3) * 64 + lane) * 8);
#pragma unroll
    for (int rt = 0; rt < 4; ++rt) {
      int m = rgrp * 64 + rt * 16 + colb;
      unsigned int off = (unsigned int)(m * 64 + khalf * 16) ^ (unsigned int)((m & 3) << 4);
      bf8 a = *reinterpret_cast<const bf8*>(ldsIn + off);
      acc[rt][0] = __builtin_amdgcn_mfma_f32_16x16x32_bf16(w0, a, acc[rt][0], 0, 0, 0);
      acc[rt][1] = __builtin_amdgcn_mfma_f32_16x16x32_bf16(w1, a, acc[rt][1], 0, 0, 0);
      acc[rt][2] = __builtin_amdgcn_mfma_f32_16x16x32_bf16(w2, a, acc[rt][2], 0, 0, 0);
      acc[rt][3] = __builtin_amdgcn_mfma_f32_16x16x32_bf16(w3, a, acc[rt][3], 0, 0, 0);
    }
    ACT_STORE(b0);                       // first write to ldsAct: no barrier needed
  }
  __syncthreads();

  const unsigned short* wb1 = wp + W0P_ELEMS;
  const unsigned short* wb2 = wp + W0P_ELEMS + W1P_ELEMS;
  const unsigned short* w3p = wp + W0P_ELEMS + 2 * W1P_ELEMS;

  // ======== layer 1 (in-place: read, barrier, store, barrier) ========
  DENSE256(wb1);
  __syncthreads();
  ACT_STORE(b1);
  __syncthreads();

  // ======== layer 2 ========
  DENSE256(wb2);
  __syncthreads();
  ACT_STORE(b2);
  __syncthreads();

  // ======== layer 3: 256 -> 1 via MFMA with zero-padded W3^T (cgrp 0 only) ====
  if (cgrp == 0) {
    fx4 a30 = fx4{0.f, 0.f, 0.f, 0.f};
    fx4 a31 = fx4{0.f, 0.f, 0.f, 0.f};
    fx4 a32 = fx4{0.f, 0.f, 0.f, 0.f};
    fx4 a33 = fx4{0.f, 0.f, 0.f, 0.f};
#pragma unroll
    for (int kt = 0; kt < 8; ++kt) {
      bf8 w3f = *reinterpret_cast<const bf8*>(w3p + (kt * 64 + lane) * 8);
#pragma unroll
      for (int rt = 0; rt < 4; ++rt) {
        int m = rgrp * 64 + rt * 16 + colb;
        unsigned int off = ((unsigned int)(m * 512 + kt * 64 + khalf * 16))
                         ^ ((unsigned int)((m & 15) << 4));
        bf8 a = *reinterpret_cast<const bf8*>(ldsAct + off);
        if      (rt == 0) a30 = __builtin_amdgcn_mfma_f32_16x16x32_bf16(w3f, a, a30, 0, 0, 0);
        else if (rt == 1) a31 = __builtin_amdgcn_mfma_f32_16x16x32_bf16(w3f, a, a31, 0, 0, 0);
        else if (rt == 2) a32 = __builtin_amdgcn_mfma_f32_16x16x32_bf16(w3f, a, a32, 0, 0, 0);
        else              a33 = __builtin_amdgcn_mfma_f32_16x16x32_bf16(w3f, a, a33, 0, 0, 0);
      }
    }
    if (lane < 16) {
      float bias3 = b3[0];
#pragma unroll
      for (int rt = 0; rt < 4; ++rt) {
        float y = ((rt == 0) ? a30[0] : (rt == 1) ? a31[0] : (rt == 2) ? a32[0] : a33[0]) + bias3;
        float f = (y > 0.f) ? (y + 1.f) : expf(y);   // elu(y)+1
        fbuf[R0 + rgrp * 64 + rt * 16 + lane] = f;
      }
    }
  }
}

// ---------------- kernel 3: Clenshaw-Curtis reduction -> z, jac ----------------
__global__ void reduce_kernel(const float* __restrict__ x, const float* __restrict__ h,
                              const float* __restrict__ fbuf, float* __restrict__ out) {
  __shared__ float ccw[NS];
  int tid = threadIdx.x;
  if (tid < NS) {
    double acc = 0.0;
#pragma unroll
    for (int i = 0; i <= 20; i += 2) {
      double wi = (i == 0) ? 1.0 : 2.0 / (1.0 - (double)(i * i));
      acc += cos((double)(i * tid) * 3.141592653589793 / 20.0) * wi;
    }
    double edge = (tid == 0 || tid == 20) ? 0.5 : 1.0;
    ccw[tid] = (float)(acc * 0.1 * edge);          // * 2/nb_steps * edge
  }
  __syncthreads();
  int t = blockIdx.x * blockDim.x + tid;
  if (t >= NBD) return;
  const float* fb = fbuf + t * NS;
  float acc = 0.f;
#pragma unroll
  for (int i = 0; i < NS; ++i) acc += fb[i] * ccw[i];
  float z = acc * x[t] * 0.5f + h[t * NCOND];
  out[t] = z;                     // z_est + h[:,:,0]
  out[NBD + t] = fb[0];           // jac = f at node s=0 (steps[0]==1 -> input == [x,h])
}

// ---------------- launcher ----------------
extern "C" void kernel_launch(void* const* d_in, const int* in_sizes, int n_in,
                              void* d_out, int out_size, void* d_ws, size_t ws_size,
                              hipStream_t stream) {
  (void)in_sizes; (void)n_in; (void)out_size; (void)ws_size;
  const float* x  = (const float*)d_in[0];
  const float* h  = (const float*)d_in[1];
  const float* W0 = (const float*)d_in[2];
  const float* b0 = (const float*)d_in[3];
  const float* W1 = (const float*)d_in[4];
  const float* b1 = (const float*)d_in[5];
  const float* W2 = (const float*)d_in[6];
  const float* b2 = (const float*)d_in[7];
  const float* W3 = (const float*)d_in[8];
  const float* b3 = (const float*)d_in[9];

  unsigned short* wp = (unsigned short*)d_ws;
  float* fbuf = (float*)((char*)d_ws + WP_TOTAL * sizeof(unsigned short));
  float* out  = (float*)d_out;

  prep_pack<<<(WP_TOTAL / 8 + 255) / 256, 256, 0, stream>>>(W0, W1, W2, W3, wp);
  mlp_kernel<<<NBLOCKS, 512, 0, stream>>>(x, h, b0, b1, b2, b3, wp, fbuf);
  reduce_kernel<<<(NBD + 255) / 256, 256, 0, stream>>>(x, h, fbuf, out);
}

// Round 7
// 118.633 us; speedup vs baseline: 1.9163x; 1.0429x over previous
//
#include <hip/hip_runtime.h>
#include <math.h>

// ---------------- problem constants ----------------
#define NB        512
#define ND        32
#define NCOND     30
#define NS        21                  // NB_STEPS+1 quadrature nodes
#define NBD       (NB*ND)             // 16384
#define NROWS     (NBD*NS)            // 344064 MLP evaluations
#define MBLK      128                 // rows per block
#define NBLOCKS   (NROWS/MBLK)        // 2688

// packed-weight element counts (ushort)
#define W0P_ELEMS (1*16*64*8)         // 8192
#define W1P_ELEMS (8*16*64*8)         // 65536
#define W3P_ELEMS (8*64*8)            // 4096  (zero-padded W3 as A-fragments)
#define WP_TOTAL  (W0P_ELEMS + 2*W1P_ELEMS + W3P_ELEMS)  // 143360

typedef __bf16 bf8 __attribute__((ext_vector_type(8)));
typedef float  fx4 __attribute__((ext_vector_type(4)));
typedef unsigned short us8 __attribute__((ext_vector_type(8)));

__device__ __forceinline__ unsigned short f2bf(float f) {
  unsigned int u = __float_as_uint(f);
  u += 0x7FFFu + ((u >> 16) & 1u);        // round-to-nearest-even
  return (unsigned short)(u >> 16);
}

// ---------------- kernel 1: pack weights to bf16 MFMA fragment order ----------
__global__ void prep_pack(const float* __restrict__ W0,
                          const float* __restrict__ W1,
                          const float* __restrict__ W2,
                          const float* __restrict__ W3,
                          unsigned short* __restrict__ wp) {
  int t = blockIdx.x * blockDim.x + threadIdx.x;   // one thread = one 8-elem frag
  if (t >= WP_TOTAL / 8) return;
  int base = t * 8;
  us8 out;
  if (base >= W0P_ELEMS + 2 * W1P_ELEMS) {         // W3 region
    int rem  = base - (W0P_ELEMS + 2 * W1P_ELEMS);
    int lane = (rem >> 3) & 63;
    int ktl  = rem >> 9;
    int k0   = ktl * 32 + (lane >> 4) * 8;
#pragma unroll
    for (int i = 0; i < 8; ++i)
      out[i] = ((lane & 15) == 0) ? f2bf(W3[k0 + i]) : (unsigned short)0;
  } else {
    const float* W; int rem, K;
    if (base < W0P_ELEMS)                  { W = W0; rem = base;                 K = 31;  }
    else if (base < W0P_ELEMS + W1P_ELEMS) { W = W1; rem = base - W0P_ELEMS;     K = 256; }
    else                                   { W = W2; rem = base - W0P_ELEMS - W1P_ELEMS; K = 256; }
    int lane = (rem >> 3) & 63;
    int ct   = (rem >> 9) & 15;
    int ktl  =  rem >> 13;
    int j  = ct * 16 + (lane & 15);
    int k0 = ktl * 32 + (lane >> 4) * 8;
#pragma unroll
    for (int i = 0; i < 8; ++i) {
      int k = k0 + i;
      out[i] = (k < K) ? f2bf(W[k * 256 + j]) : (unsigned short)0;
    }
  }
  *reinterpret_cast<us8*>(wp + base) = out;
}

// ---------------- fused MLP kernel ----------------
// Round-6 structure (8 waves = 2 rgrp x 4 cgrp, 128 rows, in-place 64KB act
// buffer) + depth-2 software pipeline on the weight stream: two 4-frag
// register slots (wa*, wb*), each K-step consumes a slot loaded 2 steps ago;
// the last two K-steps of each layer prefetch the NEXT layer's kt0/kt1 so the
// loads straddle the store barriers (plain global->VGPR loads are not drained
// at s_barrier). setprio(1) around each 16-MFMA cluster (T5).

#define ACC_ZERO                                                                 \
  _Pragma("unroll")                                                              \
  for (int rt = 0; rt < 4; ++rt)                                                 \
    _Pragma("unroll")                                                            \
    for (int ct = 0; ct < 4; ++ct) acc[rt][ct] = fx4{0.f, 0.f, 0.f, 0.f};

#define LOADW4(S0,S1,S2,S3, WB, KT)                                              \
  S0 = *reinterpret_cast<const bf8*>((WB) + (((KT) * 16 + cgrp * 4 + 0) * 64 + lane) * 8); \
  S1 = *reinterpret_cast<const bf8*>((WB) + (((KT) * 16 + cgrp * 4 + 1) * 64 + lane) * 8); \
  S2 = *reinterpret_cast<const bf8*>((WB) + (((KT) * 16 + cgrp * 4 + 2) * 64 + lane) * 8); \
  S3 = *reinterpret_cast<const bf8*>((WB) + (((KT) * 16 + cgrp * 4 + 3) * 64 + lane) * 8);

#define KSTEP(W0_,W1_,W2_,W3_, KT)                                               \
  {                                                                              \
    int m0 = rgrp * 64 +  0 + colb;                                              \
    int m1 = rgrp * 64 + 16 + colb;                                              \
    int m2 = rgrp * 64 + 32 + colb;                                              \
    int m3 = rgrp * 64 + 48 + colb;                                              \
    bf8 a0 = *reinterpret_cast<const bf8*>(ldsAct + (((unsigned)(m0 * 512 + (KT) * 64 + khalf * 16)) ^ ((unsigned)((m0 & 15) << 4)))); \
    bf8 a1 = *reinterpret_cast<const bf8*>(ldsAct + (((unsigned)(m1 * 512 + (KT) * 64 + khalf * 16)) ^ ((unsigned)((m1 & 15) << 4)))); \
    bf8 a2 = *reinterpret_cast<const bf8*>(ldsAct + (((unsigned)(m2 * 512 + (KT) * 64 + khalf * 16)) ^ ((unsigned)((m2 & 15) << 4)))); \
    bf8 a3 = *reinterpret_cast<const bf8*>(ldsAct + (((unsigned)(m3 * 512 + (KT) * 64 + khalf * 16)) ^ ((unsigned)((m3 & 15) << 4)))); \
    __builtin_amdgcn_s_setprio(1);                                               \
    acc[0][0] = __builtin_amdgcn_mfma_f32_16x16x32_bf16(W0_, a0, acc[0][0], 0, 0, 0); \
    acc[0][1] = __builtin_amdgcn_mfma_f32_16x16x32_bf16(W1_, a0, acc[0][1], 0, 0, 0); \
    acc[0][2] = __builtin_amdgcn_mfma_f32_16x16x32_bf16(W2_, a0, acc[0][2], 0, 0, 0); \
    acc[0][3] = __builtin_amdgcn_mfma_f32_16x16x32_bf16(W3_, a0, acc[0][3], 0, 0, 0); \
    acc[1][0] = __builtin_amdgcn_mfma_f32_16x16x32_bf16(W0_, a1, acc[1][0], 0, 0, 0); \
    acc[1][1] = __builtin_amdgcn_mfma_f32_16x16x32_bf16(W1_, a1, acc[1][1], 0, 0, 0); \
    acc[1][2] = __builtin_amdgcn_mfma_f32_16x16x32_bf16(W2_, a1, acc[1][2], 0, 0, 0); \
    acc[1][3] = __builtin_amdgcn_mfma_f32_16x16x32_bf16(W3_, a1, acc[1][3], 0, 0, 0); \
    acc[2][0] = __builtin_amdgcn_mfma_f32_16x16x32_bf16(W0_, a2, acc[2][0], 0, 0, 0); \
    acc[2][1] = __builtin_amdgcn_mfma_f32_16x16x32_bf16(W1_, a2, acc[2][1], 0, 0, 0); \
    acc[2][2] = __builtin_amdgcn_mfma_f32_16x16x32_bf16(W2_, a2, acc[2][2], 0, 0, 0); \
    acc[2][3] = __builtin_amdgcn_mfma_f32_16x16x32_bf16(W3_, a2, acc[2][3], 0, 0, 0); \
    acc[3][0] = __builtin_amdgcn_mfma_f32_16x16x32_bf16(W0_, a3, acc[3][0], 0, 0, 0); \
    acc[3][1] = __builtin_amdgcn_mfma_f32_16x16x32_bf16(W1_, a3, acc[3][1], 0, 0, 0); \
    acc[3][2] = __builtin_amdgcn_mfma_f32_16x16x32_bf16(W2_, a3, acc[3][2], 0, 0, 0); \
    acc[3][3] = __builtin_amdgcn_mfma_f32_16x16x32_bf16(W3_, a3, acc[3][3], 0, 0, 0); \
    __builtin_amdgcn_s_setprio(0);                                               \
  }

// K-steps 0..7, consuming alternating slots, prefetching kt+2 (then next layer)
#define DENSE_PIPE(WB, NWB)                                                      \
  KSTEP(wa0,wa1,wa2,wa3, 0) LOADW4(wa0,wa1,wa2,wa3, WB, 2)                       \
  KSTEP(wb0,wb1,wb2,wb3, 1) LOADW4(wb0,wb1,wb2,wb3, WB, 3)                       \
  KSTEP(wa0,wa1,wa2,wa3, 2) LOADW4(wa0,wa1,wa2,wa3, WB, 4)                       \
  KSTEP(wb0,wb1,wb2,wb3, 3) LOADW4(wb0,wb1,wb2,wb3, WB, 5)                       \
  KSTEP(wa0,wa1,wa2,wa3, 4) LOADW4(wa0,wa1,wa2,wa3, WB, 6)                       \
  KSTEP(wb0,wb1,wb2,wb3, 5) LOADW4(wb0,wb1,wb2,wb3, WB, 7)                       \
  KSTEP(wa0,wa1,wa2,wa3, 6) LOADW4(wa0,wa1,wa2,wa3, NWB, 0)                      \
  KSTEP(wb0,wb1,wb2,wb3, 7) LOADW4(wb0,wb1,wb2,wb3, NWB, 1)

#define DENSE_LAST(WB)                                                           \
  KSTEP(wa0,wa1,wa2,wa3, 0) LOADW4(wa0,wa1,wa2,wa3, WB, 2)                       \
  KSTEP(wb0,wb1,wb2,wb3, 1) LOADW4(wb0,wb1,wb2,wb3, WB, 3)                       \
  KSTEP(wa0,wa1,wa2,wa3, 2) LOADW4(wa0,wa1,wa2,wa3, WB, 4)                       \
  KSTEP(wb0,wb1,wb2,wb3, 3) LOADW4(wb0,wb1,wb2,wb3, WB, 5)                       \
  KSTEP(wa0,wa1,wa2,wa3, 4) LOADW4(wa0,wa1,wa2,wa3, WB, 6)                       \
  KSTEP(wb0,wb1,wb2,wb3, 5) LOADW4(wb0,wb1,wb2,wb3, WB, 7)                       \
  KSTEP(wa0,wa1,wa2,wa3, 6)                                                      \
  KSTEP(wb0,wb1,wb2,wb3, 7)

// bias + ReLU + bf16-pack + ds_write_b64 store of acc into ldsAct
#define ACT_STORE(BIAS)                                                          \
  {                                                                              \
    float4 bv0 = *reinterpret_cast<const float4*>((BIAS) + (cgrp * 4 + 0) * 16 + khalf * 4); \
    float4 bv1 = *reinterpret_cast<const float4*>((BIAS) + (cgrp * 4 + 1) * 16 + khalf * 4); \
    float4 bv2 = *reinterpret_cast<const float4*>((BIAS) + (cgrp * 4 + 2) * 16 + khalf * 4); \
    float4 bv3 = *reinterpret_cast<const float4*>((BIAS) + (cgrp * 4 + 3) * 16 + khalf * 4); \
    _Pragma("unroll")                                                            \
    for (int rt = 0; rt < 4; ++rt) {                                             \
      int m = rgrp * 64 + rt * 16 + colb;                                        \
      unsigned int sbase = (unsigned int)(m * 512);                              \
      unsigned int swz   = (unsigned int)((m & 15) << 4);                        \
      _Pragma("unroll")                                                          \
      for (int ct = 0; ct < 4; ++ct) {                                           \
        float4 bv = (ct == 0) ? bv0 : (ct == 1) ? bv1 : (ct == 2) ? bv2 : bv3;   \
        int n0 = (cgrp * 4 + ct) * 16 + khalf * 4;                               \
        float v0 = fmaxf(acc[rt][ct][0] + bv.x, 0.f);                            \
        float v1 = fmaxf(acc[rt][ct][1] + bv.y, 0.f);                            \
        float v2 = fmaxf(acc[rt][ct][2] + bv.z, 0.f);                            \
        float v3 = fmaxf(acc[rt][ct][3] + bv.w, 0.f);                            \
        unsigned int p0, p1;                                                     \
        asm("v_cvt_pk_bf16_f32 %0, %1, %2" : "=v"(p0) : "v"(v0), "v"(v1));       \
        asm("v_cvt_pk_bf16_f32 %0, %1, %2" : "=v"(p1) : "v"(v2), "v"(v3));       \
        uint2 pk; pk.x = p0; pk.y = p1;                                          \
        *reinterpret_cast<uint2*>(ldsAct + ((sbase + (unsigned int)(n0 * 2)) ^ swz)) = pk; \
      }                                                                          \
    }                                                                            \
  }

__global__ __launch_bounds__(512, 1)
void mlp_kernel(const float* __restrict__ x, const float* __restrict__ h,
                const float* __restrict__ b0, const float* __restrict__ b1,
                const float* __restrict__ b2, const float* __restrict__ b3,
                const unsigned short* __restrict__ wp,
                float* __restrict__ fbuf) {
  __shared__ __align__(16) unsigned char ldsAct[128 * 512];  // 64 KiB
  __shared__ __align__(16) unsigned char ldsIn[128 * 64];    // 8 KiB

  int tid  = threadIdx.x;
  int wv   = tid >> 6;
  int lane = tid & 63;
  int rgrp = wv >> 2;            // 0..1 : 64-row half
  int cgrp = wv & 3;             // 0..3 : 64-neuron group
  int colb  = lane & 15;
  int khalf = lane >> 4;
  int R0 = blockIdx.x * MBLK;

  const unsigned short* wb1p = wp + W0P_ELEMS;
  const unsigned short* wb2p = wp + W0P_ELEMS + W1P_ELEMS;
  const unsigned short* w3p  = wp + W0P_ELEMS + 2 * W1P_ELEMS;

  bf8 wa0, wa1, wa2, wa3, wb0, wb1, wb2, wb3;
  // layer-0 weights (single K-step) into slot A, issued before input staging
  LOADW4(wa0, wa1, wa2, wa3, wp, 0);

  // ---- stage layer-0 input [128 rows][32 bf16] into ldsIn ----
  {
    int r = tid >> 2;                   // 0..127
    int q = tid & 3;                    // 8-col chunk
    int gr = R0 + r;
    unsigned int bd = (unsigned int)gr / NS;
    int s = gr - (int)bd * NS;
    float xv = x[bd];
    float node = xv * (cosf((float)s * 0.15707963267948966f) + 1.0f) * 0.5f;
    const float* hrow = h + bd * NCOND;
    us8 au;
#pragma unroll
    for (int i = 0; i < 8; ++i) {
      int c = q * 8 + i;
      float v;
      if (c == 0)       v = node;
      else if (c <= 30) v = hrow[c - 1];
      else              v = 0.0f;
      au[i] = f2bf(v);
    }
    unsigned int off = (unsigned int)(r * 64 + q * 16) ^ (unsigned int)((r & 3) << 4);
    *reinterpret_cast<us8*>(ldsIn + off) = au;
  }
  __syncthreads();

  fx4 acc[4][4];

  // ======== layer 0: K=32 (one K-step), read ldsIn, store ldsAct ========
  {
    ACC_ZERO;
#pragma unroll
    for (int rt = 0; rt < 4; ++rt) {
      int m = rgrp * 64 + rt * 16 + colb;
      unsigned int off = (unsigned int)(m * 64 + khalf * 16) ^ (unsigned int)((m & 3) << 4);
      bf8 a = *reinterpret_cast<const bf8*>(ldsIn + off);
      acc[rt][0] = __builtin_amdgcn_mfma_f32_16x16x32_bf16(wa0, a, acc[rt][0], 0, 0, 0);
      acc[rt][1] = __builtin_amdgcn_mfma_f32_16x16x32_bf16(wa1, a, acc[rt][1], 0, 0, 0);
      acc[rt][2] = __builtin_amdgcn_mfma_f32_16x16x32_bf16(wa2, a, acc[rt][2], 0, 0, 0);
      acc[rt][3] = __builtin_amdgcn_mfma_f32_16x16x32_bf16(wa3, a, acc[rt][3], 0, 0, 0);
    }
    // prefetch layer-1 kt0/kt1 across the store + barrier
    LOADW4(wa0, wa1, wa2, wa3, wb1p, 0);
    LOADW4(wb0, wb1, wb2, wb3, wb1p, 1);
    ACT_STORE(b0);                       // first write to ldsAct: no barrier needed
  }
  __syncthreads();

  // ======== layer 1 (in-place: read, barrier, store, barrier) ========
  ACC_ZERO;
  DENSE_PIPE(wb1p, wb2p);                // tail prefetches layer-2 kt0/kt1
  __syncthreads();
  ACT_STORE(b1);
  __syncthreads();

  // ======== layer 2 ========
  ACC_ZERO;
  DENSE_LAST(wb2p);
  __syncthreads();
  ACT_STORE(b2);
  __syncthreads();

  // ======== layer 3: 256 -> 1 via MFMA with zero-padded W3^T (cgrp 0 only) ====
  if (cgrp == 0) {
    fx4 a30 = fx4{0.f, 0.f, 0.f, 0.f};
    fx4 a31 = fx4{0.f, 0.f, 0.f, 0.f};
    fx4 a32 = fx4{0.f, 0.f, 0.f, 0.f};
    fx4 a33 = fx4{0.f, 0.f, 0.f, 0.f};
#pragma unroll
    for (int kt = 0; kt < 8; ++kt) {
      bf8 w3f = *reinterpret_cast<const bf8*>(w3p + (kt * 64 + lane) * 8);
#pragma unroll
      for (int rt = 0; rt < 4; ++rt) {
        int m = rgrp * 64 + rt * 16 + colb;
        unsigned int off = ((unsigned int)(m * 512 + kt * 64 + khalf * 16))
                         ^ ((unsigned int)((m & 15) << 4));
        bf8 a = *reinterpret_cast<const bf8*>(ldsAct + off);
        if      (rt == 0) a30 = __builtin_amdgcn_mfma_f32_16x16x32_bf16(w3f, a, a30, 0, 0, 0);
        else if (rt == 1) a31 = __builtin_amdgcn_mfma_f32_16x16x32_bf16(w3f, a, a31, 0, 0, 0);
        else if (rt == 2) a32 = __builtin_amdgcn_mfma_f32_16x16x32_bf16(w3f, a, a32, 0, 0, 0);
        else              a33 = __builtin_amdgcn_mfma_f32_16x16x32_bf16(w3f, a, a33, 0, 0, 0);
      }
    }
    if (lane < 16) {
      float bias3 = b3[0];
#pragma unroll
      for (int rt = 0; rt < 4; ++rt) {
        float y = ((rt == 0) ? a30[0] : (rt == 1) ? a31[0] : (rt == 2) ? a32[0] : a33[0]) + bias3;
        float f = (y > 0.f) ? (y + 1.f) : expf(y);   // elu(y)+1
        fbuf[R0 + rgrp * 64 + rt * 16 + lane] = f;
      }
    }
  }
}

// ---------------- kernel 3: Clenshaw-Curtis reduction -> z, jac ----------------
__global__ void reduce_kernel(const float* __restrict__ x, const float* __restrict__ h,
                              const float* __restrict__ fbuf, float* __restrict__ out) {
  __shared__ float ccw[NS];
  int tid = threadIdx.x;
  if (tid < NS) {
    double acc = 0.0;
#pragma unroll
    for (int i = 0; i <= 20; i += 2) {
      double wi = (i == 0) ? 1.0 : 2.0 / (1.0 - (double)(i * i));
      acc += cos((double)(i * tid) * 3.141592653589793 / 20.0) * wi;
    }
    double edge = (tid == 0 || tid == 20) ? 0.5 : 1.0;
    ccw[tid] = (float)(acc * 0.1 * edge);          // * 2/nb_steps * edge
  }
  __syncthreads();
  int t = blockIdx.x * blockDim.x + tid;
  if (t >= NBD) return;
  const float* fb = fbuf + t * NS;
  float acc = 0.f;
#pragma unroll
  for (int i = 0; i < NS; ++i) acc += fb[i] * ccw[i];
  float z = acc * x[t] * 0.5f + h[t * NCOND];
  out[t] = z;                     // z_est + h[:,:,0]
  out[NBD + t] = fb[0];           // jac = f at node s=0 (steps[0]==1 -> input == [x,h])
}

// ---------------- launcher ----------------
extern "C" void kernel_launch(void* const* d_in, const int* in_sizes, int n_in,
                              void* d_out, int out_size, void* d_ws, size_t ws_size,
                              hipStream_t stream) {
  (void)in_sizes; (void)n_in; (void)out_size; (void)ws_size;
  const float* x  = (const float*)d_in[0];
  const float* h  = (const float*)d_in[1];
  const float* W0 = (const float*)d_in[2];
  const float* b0 = (const float*)d_in[3];
  const float* W1 = (const float*)d_in[4];
  const float* b1 = (const float*)d_in[5];
  const float* W2 = (const float*)d_in[6];
  const float* b2 = (const float*)d_in[7];
  const float* W3 = (const float*)d_in[8];
  const float* b3 = (const float*)d_in[9];

  unsigned short* wp = (unsigned short*)d_ws;
  float* fbuf = (float*)((char*)d_ws + WP_TOTAL * sizeof(unsigned short));
  float* out  = (float*)d_out;

  prep_pack<<<(WP_TOTAL / 8 + 255) / 256, 256, 0, stream>>>(W0, W1, W2, W3, wp);
  mlp_kernel<<<NBLOCKS, 512, 0, stream>>>(x, h, b0, b1, b2, b3, wp, fbuf);
  reduce_kernel<<<(NBD + 255) / 256, 256, 0, stream>>>(x, h, fbuf, out);
}